// Round 4
// baseline (90.353 us; speedup 1.0000x reference)
//
#include <hip/hip_runtime.h>

// Problem: N=4096 rows, D=64 feats, 10 classes.
// sym KL: sym_ij = 0.25*(H_i . Hp_j + s_i + s_j + det_ij + det_ji - 128)
// per-feature packed K layout (K=256):
//   H[r][4d+{0,1,2,3}] = { var+mu^2, -2mu, 1/var, mu/var }   (F0,F1,G0,G1)
// Hp is not stored: Hp[e] = H[pi(e)], pi swaps components c<->c+2 within each
// 4-group; on a lane's 8-element fragment it is the 32-bit register
// permutation [v1,v0,v3,v2].
//
// Storage is MFMA-FRAGMENT-MAJOR: Hf[tile=r>>5][k=e>>4][(r&31)*16 + (e&15)]
// so each k-step fragment load is 64 lanes x 16 B = 1 KB contiguous.
//
// R9 vs R8: phase 2 restructured for LATENCY HIDING. Evidence: R7 VGPR=68
// (= 64 acc + scratch) proved the serial K-loop ran load->200cy-L2-wait->MFMA
// with zero staging; at 2 waves/SIMD that's ~40% hidden -> pair ~15-20 us vs
// ~4 us L2-BW floor. New shape: one 64x64 tile per 1-WAVE block, 2080 blocks
// (same 133 MB L2 traffic -- intra-block wave redundancy of the 128-tile
// exactly offsets the smaller tile), __launch_bounds__(64,4) -> <=128 VGPR
// tier -> 16 waves/CU capacity, no hot-path barriers, natural balance.
// Ping-pong prefetch uses NAMED scalars (no arrays -> no scratch risk);
// full unroll makes the x=y handoff an SSA rename.

#define N 4096
#define D 64
#define KH 256
#define MT 64              // tile side, 1 wave per tile
#define TILES 64           // 4096/64
#define NT 2080            // 64*65/2 inclusive-triangle tiles
#define DET_EPS 1e-8f

typedef short bf16x8 __attribute__((ext_vector_type(8)));
typedef float f32x16 __attribute__((ext_vector_type(16)));

// ws byte layout
#define WS_H    0                       // ushort[N/32][16][512] = 2 MB (frag-major)
#define WS_PSL  (N * KH * 2)            // float4[N] = 64 KB
#define WS_PART (WS_PSL + N * 16)       // float[2*NT] = 16.6 KB

static __device__ __forceinline__ unsigned short f2bf(float x) {
  // round-to-nearest-even bf16
  unsigned int u = __float_as_uint(x);
  unsigned int r = (u + 0x7FFFu + ((u >> 16) & 1u)) >> 16;
  return (unsigned short)r;
}

static __device__ __forceinline__ f32x16 mfma_bf16(bf16x8 a, bf16x8 b, f32x16 c) {
  return __builtin_amdgcn_mfma_f32_32x32x16_bf16(a, b, c, 0, 0, 0);
}

// ---------------------------------------------------------------------------
// Kernel 1: per-row precompute. 1024 blocks x 256 thr; one wave per row.
// Stores Hf (frag-major) and PSL = {p, 1/(p+eps), 0.25*s-16, label}.
__global__ __launch_bounds__(256) void precompute_kernel(
    const float* __restrict__ mu, const float* __restrict__ var,
    const int* __restrict__ labels,
    unsigned short* __restrict__ Hf, float4* __restrict__ PSL) {
  const int t = threadIdx.x;
  const int lane = t & 63;   // feature d
  const int w = t >> 6;
  const int r = blockIdx.x * 4 + w;

  const float m = mu[r * D + lane];
  const float v = var[r * D + lane];
  const float g0 = 1.0f / v;
  const float f0 = v + m * m;
  const float f1 = -2.0f * m;
  const float g1 = m * g0;

  // element e = 4*d + c; frag-major idx:
  //   (r>>5)*8192 + (e>>4)*512 + (r&31)*16 + (e&15)
  const size_t base = (size_t)(r >> 5) * 8192 + (size_t)(lane >> 2) * 512
                      + (size_t)(r & 31) * 16 + (size_t)(lane & 3) * 4;
  *(ushort4*)&Hf[base] = make_ushort4(f2bf(f0), f2bf(f1), f2bf(g0), f2bf(g1));

  // wave reductions: p = prod var, s = sum mu^2/var
  float p = v;
  float s = m * m * g0;
  #pragma unroll
  for (int off = 1; off < 64; off <<= 1) {
    p *= __shfl_xor(p, off);
    s += __shfl_xor(s, off);
  }
  if (lane == 0) {
    PSL[r] = make_float4(p, 1.0f / (p + DET_EPS), 0.25f * s - 16.0f,
                         (float)labels[r]);
  }
}

// ---------------------------------------------------------------------------
// One 64x64 pair tile (it, jt), it <= jt; ONE WAVE. 2x2 grid of 32x32 MFMA
// subtiles. B fragments derived from H via in-register component swap.
// K-loop: depth-1 ping-pong prefetch with named scalar sets (SSA-renamed).
template <bool DIAG>
static __device__ __forceinline__ void tile64(
    int it, int jt, int slot,
    const unsigned short* __restrict__ Hf,
    const float4* __restrict__ PSL, float* __restrict__ partial,
    float4* sPi, float4* sPj) {
  const int i0 = it * MT, j0 = jt * MT;
  const int lane = (int)threadIdx.x & 63;
  const int l31 = lane & 31;

  // stage per-row stats {p, 1/(p+eps), 0.25*s-16, label}; 1 wave -> no barrier
  sPi[lane] = PSL[i0 + lane];
  sPj[lane] = PSL[j0 + lane];
  __syncthreads();   // 1-wave block: compiles to a waitcnt, cheap insurance

  const int slot_f = l31 * 16 + (lane >> 5) * 8;  // frag-major lane slot
  const unsigned short* pa = Hf + (size_t)(i0 >> 5) * 8192 + slot_f;
  const unsigned short* pb = Hf + (size_t)(j0 >> 5) * 8192 + slot_f;

#define LDA0(k) (*(const bf16x8*)(pa + (k) * 512))
#define LDA1(k) (*(const bf16x8*)(pa + 8192 + (k) * 512))
#define LDB0(k) (*(const bf16x8*)(pb + (k) * 512))
#define LDB1(k) (*(const bf16x8*)(pb + 8192 + (k) * 512))
  // pi(e): swap component pairs -> 32-bit reg perm [v1,v0,v3,v2]
#define PI(x) __builtin_shufflevector((x), (x), 2, 3, 0, 1, 6, 7, 4, 5)

  f32x16 C00 = {}, C01 = {}, C10 = {}, C11 = {};

  bf16x8 a0x = LDA0(0), a1x = LDA1(0), b0x = LDB0(0), b1x = LDB1(0);
  #pragma unroll
  for (int k = 0; k < 16; ++k) {
    bf16x8 a0y, a1y, b0y, b1y;
    if (k < 15) {                      // prefetch k+1 while computing k
      a0y = LDA0(k + 1); a1y = LDA1(k + 1);
      b0y = LDB0(k + 1); b1y = LDB1(k + 1);
    }
    const bf16x8 p0 = PI(b0x), p1 = PI(b1x);
    C00 = mfma_bf16(a0x, p0, C00);
    C01 = mfma_bf16(a0x, p1, C01);
    C10 = mfma_bf16(a1x, p0, C10);
    C11 = mfma_bf16(a1x, p1, C11);
    if (k < 15) {                      // SSA rename under full unroll
      a0x = a0y; a1x = a1y; b0x = b0y; b1x = b1y;
    }
  }
#undef LDA0
#undef LDA1
#undef LDB0
#undef LDB1
#undef PI

  // epilogue: C/D layout col=lane&31, row=(r&3)+8*(r>>2)+4*(lane>>5)
  const int rbase = 4 * (lane >> 5);
  float pos = 0.0f, neg = 0.0f;
  #pragma unroll
  for (int mn = 0; mn < 4; ++mn) {
    const int m = mn >> 1, n = mn & 1;
    if (DIAG && m == 1 && n == 0) continue;  // subtile entirely below diagonal
    const f32x16 C = (mn == 0) ? C00 : (mn == 1) ? C01 : (mn == 2) ? C10 : C11;
    const int jloc = n * 32 + l31;
    const float4 pj = sPj[jloc];
    #pragma unroll
    for (int r = 0; r < 16; ++r) {
      const int row = (r & 3) + 8 * (r >> 2) + rbase;
      const int iloc = m * 32 + row;
      // off-diag tiles: i0+63 < j0, so i<j holds for every element
      if (!DIAG || (i0 + iloc) < (j0 + jloc)) {
        const float4 pi = sPi[iloc];
        const float det = pj.x * pi.y + pi.x * pj.y;
        const float sym = 0.25f * (C[r] + det) + pi.z + pj.z;
        const float sig = __builtin_amdgcn_rcpf(1.0f + __expf(-sym));
        if (pi.w == pj.w) pos += sig; else neg += sig;
      }
    }
  }

  // wave reduce; lane 0 stores to the tile's private slot (no atomics)
  #pragma unroll
  for (int off = 32; off > 0; off >>= 1) {
    pos += __shfl_down(pos, off);
    neg += __shfl_down(neg, off);
  }
  if (lane == 0) {
    partial[slot]      = pos;
    partial[NT + slot] = neg;
  }
}

// ---------------------------------------------------------------------------
// Kernel 2: 2080 one-wave blocks, one 64x64 tile each.
__global__ __launch_bounds__(64, 4) void pair64_kernel(
    const unsigned short* __restrict__ Hf,
    const float4* __restrict__ PSL, float* __restrict__ partial) {
  __shared__ float4 sPi[64];
  __shared__ float4 sPj[64];

  // inclusive-triangle decode on the 64-grid: offset(it) = it*64 - it(it-1)/2
  int L = (int)blockIdx.x;
  int it = (int)((129.0f - sqrtf(16641.0f - 8.0f * (float)L)) * 0.5f);
  while (it > 0 && L < it * TILES - it * (it - 1) / 2) --it;
  while (L >= (it + 1) * TILES - (it + 1) * it / 2) ++it;
  const int jt = it + (L - (it * TILES - it * (it - 1) / 2));

  if (it == jt) tile64<true>(it, jt, L, Hf, PSL, partial, sPi, sPj);
  else          tile64<false>(it, jt, L, Hf, PSL, partial, sPi, sPj);
}

// ---------------------------------------------------------------------------
// Kernel 3: reduce per-tile slots, finalize 4 outputs.
// Full-grid sums = 2 * triangle sums (sym matrix, diag excluded).
__global__ __launch_bounds__(256) void finalize_kernel(
    const float* __restrict__ partial, float* __restrict__ out) {
  __shared__ float redp[4], redn[4];
  const int t = threadIdx.x;
  const int lane = t & 63, w = t >> 6;
  float p = 0.0f, n = 0.0f;
  for (int i = t; i < NT; i += 256) {
    p += partial[i];
    n += partial[NT + i];
  }
  #pragma unroll
  for (int off = 32; off > 0; off >>= 1) {
    p += __shfl_down(p, off);
    n += __shfl_down(n, off);
  }
  if (lane == 0) { redp[w] = p; redn[w] = n; }
  __syncthreads();
  if (t == 0) {
    const float pos = 2.0f * (redp[0] + redp[1] + redp[2] + redp[3]);
    const float neg = 2.0f * (redn[0] + redn[1] + redn[2] + redn[3]);
    out[0] = pos * (1.0f / 16777216.0f);  // mean over N*N = 2^24
    out[1] = neg * (1.0f / 16777216.0f);
    out[2] = pos;
    out[3] = neg;
  }
}

extern "C" void kernel_launch(void* const* d_in, const int* in_sizes, int n_in,
                              void* d_out, int out_size, void* d_ws, size_t ws_size,
                              hipStream_t stream) {
  const float* mu = (const float*)d_in[0];
  const float* var = (const float*)d_in[1];
  const int* labels = (const int*)d_in[2];
  float* out = (float*)d_out;
  char* ws = (char*)d_ws;

  unsigned short* Hf = (unsigned short*)(ws + WS_H);
  float4* PSL = (float4*)(ws + WS_PSL);
  float* partial = (float*)(ws + WS_PART);

  precompute_kernel<<<dim3(N / 4), dim3(256), 0, stream>>>(mu, var, labels, Hf, PSL);
  pair64_kernel<<<dim3(NT), dim3(64), 0, stream>>>(Hf, PSL, partial);
  finalize_kernel<<<dim3(1), dim3(256), 0, stream>>>(partial, out);
}

// Round 5
// 78.848 us; speedup vs baseline: 1.1459x; 1.1459x over previous
//
#include <hip/hip_runtime.h>

// Problem: N=4096 rows, D=64 feats, 10 classes.
// sym KL: sym_ij = 0.25*(H_i . Hp_j + s_i + s_j + det_ij + det_ji - 128)
// per-feature packed K layout (K=256):
//   H[r][4d+{0,1,2,3}] = { var+mu^2, -2mu, 1/var, mu/var }   (F0,F1,G0,G1)
// Hp (the {G0,G1,F0,F1} order) is NOT stored: Hp[e] = H[pi(e)] where pi swaps
// components c<->c+2 within each 4-group; pi is an involution, so
//   sum_e H_i[e]*Hp_j[e] = sum_e H_i[e]*H_j[pi(e)]
// and pi on a lane's 8-element fragment is a 32-bit register permutation
// [v1,v0,v3,v2] -- done in-register, no second array.
//
// Storage is MFMA-FRAGMENT-MAJOR: Hf[tile=r>>5][k=e>>4][(r&31)*16 + (e&15)]
// so each k-step fragment load is 64 lanes x 16 B = 1 KB contiguous.
//
// R10 = R5 (best measured, 78.1 us) + ONE change: the K-loop is chunked
// (4 chunks x 4 k-steps) with asm volatile("" ::: "memory") fences pinning
// each chunk's load-issue point. Evidence trail: R7 VGPR=68 and R9 VGPR=64
// prove hipcc sinks source-level prefetch loads back to just-before-use
// (zero staging registers allocated), leaving the K-loop serialized at
// ~200-400 cy exposed L2 latency per step with only 8 waves/CU to hide it
// (MfmaUtil ~3%). A memory-clobber asm is a wall loads cannot cross, while
// keeping loads compiler-visible so hipcc emits its own COUNTED vmcnt(16)
// before first use -- chunk c+1 stays in flight during chunk c's MFMAs.
// Success check: pair_kernel VGPR ~180-210 (staging finally allocated).

#define N 4096
#define D 64
#define KH 256
#define MT 128             // pair block tile side
#define TILES2 32          // 4096/128
#define NBLK2 528          // TILES2*(TILES2+1)/2 upper-tri blocks
#define DET_EPS 1e-8f

typedef short bf16x8 __attribute__((ext_vector_type(8)));
typedef float f32x16 __attribute__((ext_vector_type(16)));

// ws byte layout
#define WS_H    0                       // ushort[N/32][16][512] = 2 MB (frag-major)
#define WS_PSL  (N * KH * 2)            // float4[N] = 64 KB
#define WS_PART (WS_PSL + N * 16)       // float[2*NBLK2]

static __device__ __forceinline__ unsigned short f2bf(float x) {
  // round-to-nearest-even bf16
  unsigned int u = __float_as_uint(x);
  unsigned int r = (u + 0x7FFFu + ((u >> 16) & 1u)) >> 16;
  return (unsigned short)r;
}

static __device__ __forceinline__ f32x16 mfma_bf16(bf16x8 a, bf16x8 b, f32x16 c) {
  return __builtin_amdgcn_mfma_f32_32x32x16_bf16(a, b, c, 0, 0, 0);
}

// ---------------------------------------------------------------------------
// Kernel 1: per-row precompute. 1024 blocks x 256 thr; one wave per row.
// Stores Hf (frag-major) and PSL = {p, 1/(p+eps), 0.25*s-16, label}.
__global__ __launch_bounds__(256) void precompute_kernel(
    const float* __restrict__ mu, const float* __restrict__ var,
    const int* __restrict__ labels,
    unsigned short* __restrict__ Hf, float4* __restrict__ PSL) {
  const int t = threadIdx.x;
  const int lane = t & 63;   // feature d
  const int w = t >> 6;
  const int r = blockIdx.x * 4 + w;

  const float m = mu[r * D + lane];
  const float v = var[r * D + lane];
  const float g0 = 1.0f / v;
  const float f0 = v + m * m;
  const float f1 = -2.0f * m;
  const float g1 = m * g0;

  // element e = 4*d + c; frag-major idx:
  //   (r>>5)*8192 + (e>>4)*512 + (r&31)*16 + (e&15)
  // lane d writes e = 4d..4d+3 -> 4 contiguous ushorts.
  const size_t base = (size_t)(r >> 5) * 8192 + (size_t)(lane >> 2) * 512
                      + (size_t)(r & 31) * 16 + (size_t)(lane & 3) * 4;
  *(ushort4*)&Hf[base] = make_ushort4(f2bf(f0), f2bf(f1), f2bf(g0), f2bf(g1));

  // wave reductions: p = prod var, s = sum mu^2/var
  float p = v;
  float s = m * m * g0;
  #pragma unroll
  for (int off = 1; off < 64; off <<= 1) {
    p *= __shfl_xor(p, off);
    s += __shfl_xor(s, off);
  }
  if (lane == 0) {
    PSL[r] = make_float4(p, 1.0f / (p + DET_EPS), 0.25f * s - 16.0f,
                         (float)labels[r]);
  }
}

// ---------------------------------------------------------------------------
// Kernel 2: upper-tri 128x128 pair tiles. 4 waves; wave w = quadrant
// (sr=w>>1, sc=w&1), each wave computes a 2x2 grid of 32x32 MFMA subtiles.
// B fragments derived from H via in-register component swap (see header).
__global__ __launch_bounds__(256, 2) void pair_kernel(
    const unsigned short* __restrict__ Hf,
    const float4* __restrict__ PSL, float* __restrict__ partial) {
  __shared__ float4 sPi[128];
  __shared__ float4 sPj[128];
  __shared__ float red[8];

  // triangular decode: block L -> (it, jt), it <= jt  (32x32 tile grid)
  int L = (int)blockIdx.x;
  int it = (int)(32.5f - sqrtf(32.5f * 32.5f - 2.0f * (float)L));
  while (it > 0 && L < it * TILES2 - it * (it - 1) / 2) --it;
  while (L >= (it + 1) * TILES2 - (it + 1) * it / 2) ++it;
  const int jt = it + (L - (it * TILES2 - it * (it - 1) / 2));
  const int i0 = it * MT, j0 = jt * MT;

  const int t = threadIdx.x;
  const int lane = t & 63;
  const int w = t >> 6;               // 0..3
  const int sr = w >> 1, sc = w & 1;  // 64x64 quadrant of the 128x128 block

  // stage per-row stats {p, 1/(p+eps), 0.25*s-16, label}
  if (t < 128) sPi[t] = PSL[i0 + t];
  else sPj[t - 128] = PSL[j0 + t - 128];
  __syncthreads();

  const int l31 = lane & 31;
  const int slot = l31 * 16 + (lane >> 5) * 8;  // frag-major lane slot
  const unsigned short* pa = Hf + (size_t)(i0 / 32 + sr * 2) * 8192 + slot;
  const unsigned short* pb = Hf + (size_t)(j0 / 32 + sc * 2) * 8192 + slot;

  // diagonal big-tile: quadrant (1,0) is entirely below the diagonal
  const bool active = !(it == jt && w == 2);

  f32x16 C00 = {}, C01 = {}, C10 = {}, C11 = {};
  float pos = 0.0f, neg = 0.0f;

  if (active) {
    // ---- fenced, chunked K-loop: 4 chunks of 4 k-steps, 2 reg buffers ----
    // All indices compile-time after full unroll (no scratch). Fences pin
    // load-issue points; compiler still emits counted vmcnt before use.
    bf16x8 A0[2][4], A1[2][4], B0[2][4], B1[2][4];
    #pragma unroll
    for (int s = 0; s < 4; ++s) {       // preload chunk 0 (k=0..3)
      A0[0][s] = *(const bf16x8*)(pa + s * 512);
      A1[0][s] = *(const bf16x8*)(pa + 8192 + s * 512);
      B0[0][s] = *(const bf16x8*)(pb + s * 512);
      B1[0][s] = *(const bf16x8*)(pb + 8192 + s * 512);
    }
    asm volatile("" ::: "memory");      // wall: preload issued here
    #pragma unroll
    for (int c = 0; c < 4; ++c) {
      const int cur = c & 1, nxt = cur ^ 1;
      if (c < 3) {                      // issue chunk c+1 (k=4c+4..4c+7)
        #pragma unroll
        for (int s = 0; s < 4; ++s) {
          const int k = (c + 1) * 4 + s;
          A0[nxt][s] = *(const bf16x8*)(pa + k * 512);
          A1[nxt][s] = *(const bf16x8*)(pa + 8192 + k * 512);
          B0[nxt][s] = *(const bf16x8*)(pb + k * 512);
          B1[nxt][s] = *(const bf16x8*)(pb + 8192 + k * 512);
        }
      }
      asm volatile("" ::: "memory");    // wall: c+1 loads cannot sink below
      #pragma unroll
      for (int s = 0; s < 4; ++s) {
        // pi(e): swap component pairs -> 32-bit reg perm [v1,v0,v3,v2]
        const bf16x8 b0 = __builtin_shufflevector(B0[cur][s], B0[cur][s],
                                                  2, 3, 0, 1, 6, 7, 4, 5);
        const bf16x8 b1 = __builtin_shufflevector(B1[cur][s], B1[cur][s],
                                                  2, 3, 0, 1, 6, 7, 4, 5);
        C00 = mfma_bf16(A0[cur][s], b0, C00);
        C01 = mfma_bf16(A0[cur][s], b1, C01);
        C10 = mfma_bf16(A1[cur][s], b0, C10);
        C11 = mfma_bf16(A1[cur][s], b1, C11);
      }
    }

    // epilogue: C/D layout col=lane&31, row=(r&3)+8*(r>>2)+4*(lane>>5)
    const int rbase = 4 * (lane >> 5);
    #pragma unroll
    for (int mn = 0; mn < 4; ++mn) {
      const int m = mn >> 1, n = mn & 1;
      const f32x16 C = (mn == 0) ? C00 : (mn == 1) ? C01 : (mn == 2) ? C10 : C11;
      const int jloc = (sc * 2 + n) * 32 + l31;
      const int j = j0 + jloc;
      const float4 pj = sPj[jloc];
      #pragma unroll
      for (int r = 0; r < 16; ++r) {
        const int row = (r & 3) + 8 * (r >> 2) + rbase;
        const int iloc = (sr * 2 + m) * 32 + row;
        const int i = i0 + iloc;
        if (i < j) {                   // strict upper triangle only
          const float4 pi = sPi[iloc];
          const float det = pj.x * pi.y + pi.x * pj.y;
          const float sym = 0.25f * (C[r] + det) + pi.z + pj.z;
          const float sig = __builtin_amdgcn_rcpf(1.0f + __expf(-sym));
          if (pi.w == pj.w) pos += sig; else neg += sig;
        }
      }
    }
  }

  // wave reduce -> LDS -> per-block private slot store (no atomics)
  #pragma unroll
  for (int off = 32; off > 0; off >>= 1) {
    pos += __shfl_down(pos, off);
    neg += __shfl_down(neg, off);
  }
  if (lane == 0) { red[w] = pos; red[4 + w] = neg; }
  __syncthreads();
  if (t == 0) {
    partial[L]         = red[0] + red[1] + red[2] + red[3];
    partial[NBLK2 + L] = red[4] + red[5] + red[6] + red[7];
  }
}

// ---------------------------------------------------------------------------
// Kernel 3: reduce per-block slots, finalize 4 outputs.
// Full-grid sums = 2 * triangle sums (sym matrix, diag excluded).
__global__ __launch_bounds__(256) void finalize_kernel(
    const float* __restrict__ partial, float* __restrict__ out) {
  __shared__ float redp[4], redn[4];
  const int t = threadIdx.x;
  const int lane = t & 63, w = t >> 6;
  float p = 0.0f, n = 0.0f;
  for (int i = t; i < NBLK2; i += 256) {
    p += partial[i];
    n += partial[NBLK2 + i];
  }
  #pragma unroll
  for (int off = 32; off > 0; off >>= 1) {
    p += __shfl_down(p, off);
    n += __shfl_down(n, off);
  }
  if (lane == 0) { redp[w] = p; redn[w] = n; }
  __syncthreads();
  if (t == 0) {
    const float pos = 2.0f * (redp[0] + redp[1] + redp[2] + redp[3]);
    const float neg = 2.0f * (redn[0] + redn[1] + redn[2] + redn[3]);
    out[0] = pos * (1.0f / 16777216.0f);  // mean over N*N = 2^24
    out[1] = neg * (1.0f / 16777216.0f);
    out[2] = pos;
    out[3] = neg;
  }
}

extern "C" void kernel_launch(void* const* d_in, const int* in_sizes, int n_in,
                              void* d_out, int out_size, void* d_ws, size_t ws_size,
                              hipStream_t stream) {
  const float* mu = (const float*)d_in[0];
  const float* var = (const float*)d_in[1];
  const int* labels = (const int*)d_in[2];
  float* out = (float*)d_out;
  char* ws = (char*)d_ws;

  unsigned short* Hf = (unsigned short*)(ws + WS_H);
  float4* PSL = (float4*)(ws + WS_PSL);
  float* partial = (float*)(ws + WS_PART);

  precompute_kernel<<<dim3(N / 4), dim3(256), 0, stream>>>(mu, var, labels, Hf, PSL);
  pair_kernel<<<dim3(NBLK2), dim3(256), 0, stream>>>(Hf, PSL, partial);
  finalize_kernel<<<dim3(1), dim3(256), 0, stream>>>(partial, out);
}